// Round 2
// baseline (3344.847 us; speedup 1.0000x reference)
//
#include <hip/hip_runtime.h>
#include <hip/hip_bf16.h>
#include <cstdint>
#include <math.h>

using bf16 = __hip_bfloat16;
typedef __attribute__((ext_vector_type(4))) float f32x4;
typedef __attribute__((ext_vector_type(8))) short s16x8;
typedef __attribute__((ext_vector_type(4))) short s16x4;

#define AS3(p) ((__attribute__((address_space(3))) void *)(p))
#define AS1(p) ((const __attribute__((address_space(1))) void *)(p))

static constexpr int Himg = 256, Wimg = 256, Bimg = 4;
static constexpr int HWimg = Himg * Wimg;
static constexpr int Ttok = Bimg * HWimg;   // 262144 tokens

__device__ __forceinline__ void gld16(bf16* lds, const bf16* g) {
  __builtin_amdgcn_global_load_lds(AS1(g), AS3(lds), 16, 0, 0);
}

__device__ __forceinline__ unsigned short f2u(float f) {
  bf16 b = __float2bfloat16(f);
  unsigned short u; __builtin_memcpy(&u, &b, 2); return u;
}

// ---------------- prep kernels ----------------
__global__ void k_zero4k(float* p) {
  p[blockIdx.x * 256 + threadIdx.x] = 0.f;
}

__global__ void k_castf2b(const float* __restrict__ s, bf16* __restrict__ d, int n) {
  int i = blockIdx.x * 256 + threadIdx.x;
  if (i < n) d[i] = __float2bfloat16(s[i]);
}

__global__ void k_copyf(const float* __restrict__ s, float* __restrict__ d, int n) {
  int i = blockIdx.x * 256 + threadIdx.x;
  if (i < n) d[i] = s[i];
}

// conv weight permute: OIHW fp32 -> [O][tap][I] bf16
__global__ void k_permconv(const float* __restrict__ w, bf16* __restrict__ o, int I) {
  int idx = blockIdx.x * 256 + threadIdx.x;
  int tot = 256 * 9 * I;
  if (idx >= tot) return;
  int i   = idx % I;
  int rem = idx / I;
  int tap = rem % 9;
  int oc  = rem / 9;
  o[idx] = __float2bfloat16(w[(oc * I + i) * 9 + tap]);
}

// NCHW fp32 -> NHWC bf16 (32x32 LDS tile transpose)
__global__ void k_tohwc(const float* __restrict__ src, bf16* __restrict__ dst, int C) {
  int bh = blockIdx.x;
  int w0 = blockIdx.y * 32;
  int c0 = blockIdx.z * 32;
  int b = bh / Himg, h = bh % Himg;
  __shared__ float tile[32][33];
  int tid = threadIdx.x;
  int x = tid & 31, y = tid >> 5;
  const float* sp = src + (size_t)b * C * HWimg + (size_t)h * Wimg;
#pragma unroll
  for (int p = 0; p < 4; ++p) {
    int cl = y + p * 8;
    tile[cl][x] = sp[(size_t)(c0 + cl) * HWimg + w0 + x];
  }
  __syncthreads();
#pragma unroll
  for (int p = 0; p < 4; ++p) {
    int wl = y + p * 8;
    dst[((size_t)bh * Wimg + w0 + wl) * C + c0 + x] = __float2bfloat16(tile[x][wl]);
  }
}

// ---------------- fused implicit-GEMM / conv kernel ----------------
// EPI 0: outb[t*ldo+col] = bf16(acc+bias)
// EPI 1: gate[t*768+col] = bf16(sigmoid(acc+bias) * gate[t*768+col])
// EPI 2: NCHW fp32 direct store of (acc + bias + ident), via LDS transpose
template <int CIN, int TAPS, int EPI>
__global__ void __launch_bounds__(256, 2)
k_gemm(const bf16* __restrict__ Ain, const bf16* __restrict__ BT,
       const float* __restrict__ bias,
       bf16* __restrict__ outb, int ldo,
       float* __restrict__ outf, const bf16* __restrict__ ident,
       bf16* __restrict__ gate, const bf16* __restrict__ zp)
{
  constexpr int KTOT = TAPS * CIN;
  const int t0 = blockIdx.x * 128;
  const int n0 = blockIdx.y * 128;
  const int tid = threadIdx.x;
  const int wave = tid >> 6, lane = tid & 63;
  const int seg = lane & 3;
  const int rr  = lane >> 2;

  __shared__ union {
    struct { bf16 A[128 * 32]; bf16 B[128 * 32]; } s;
    float tr[32][132];
  } u;

  f32x4 acc[4][4] = {};

  const int wr = wave >> 1, wc = wave & 1;
  const int fr = lane & 15, fq = lane >> 4;

  for (int k0 = 0; k0 < KTOT; k0 += 32) {
    const int tap = k0 / CIN;
    const int c0  = k0 - tap * CIN;
    const int dy  = tap / 3 - 1, dx = tap % 3 - 1;
#pragma unroll
    for (int i = 0; i < 2; ++i) {
      const int r = wave * 32 + i * 16 + rr;
      const int t = t0 + r;
      const bf16* src;
      if (TAPS == 1) {
        src = Ain + (size_t)t * CIN + c0 + seg * 8;
      } else {
        const int h = (t >> 8) & 255, w = t & 255;
        const int hh = h + dy, ww = w + dx;
        const bool valid = ((unsigned)hh < 256u) && ((unsigned)ww < 256u);
        const long gi = (long)t + dy * Wimg + dx;
        src = valid ? (Ain + gi * CIN + c0 + seg * 8) : (zp + seg * 8);
      }
      gld16(u.s.A + (wave * 32 + i * 16) * 32, src);
    }
#pragma unroll
    for (int i = 0; i < 2; ++i) {
      const int r = wave * 32 + i * 16 + rr;
      const bf16* src = BT + (size_t)(n0 + r) * KTOT + k0 + seg * 8;
      gld16(u.s.B + (wave * 32 + i * 16) * 32, src);
    }
    __syncthreads();
    s16x8 af[4], bfrag[4];
#pragma unroll
    for (int m = 0; m < 4; ++m)
      af[m] = *(const s16x8*)(u.s.A + (wr * 64 + m * 16 + fr) * 32 + fq * 8);
#pragma unroll
    for (int n = 0; n < 4; ++n)
      bfrag[n] = *(const s16x8*)(u.s.B + (wc * 64 + n * 16 + fr) * 32 + fq * 8);
#pragma unroll
    for (int m = 0; m < 4; ++m)
#pragma unroll
      for (int n = 0; n < 4; ++n)
        acc[m][n] = __builtin_amdgcn_mfma_f32_16x16x32_bf16(af[m], bfrag[n], acc[m][n], 0, 0, 0);
    __syncthreads();
  }

  if (EPI == 2) {
    // direct NCHW fp32 store via LDS transpose chunks of 32 channels
    const int bN = t0 >> 16;
    const int hN = (t0 >> 8) & 255;
    const int w0 = t0 & 255;
#pragma unroll
    for (int chunk = 0; chunk < 4; ++chunk) {
      __syncthreads();
      if ((chunk >> 1) == wc) {
#pragma unroll
        for (int nn = 0; nn < 2; ++nn) {
          const int n = (chunk & 1) * 2 + nn;
          const int col = n0 + wc * 64 + n * 16 + fr;
          const int cl = nn * 16 + fr;
          const float bb = bias[col];
#pragma unroll
          for (int m = 0; m < 4; ++m)
#pragma unroll
            for (int j = 0; j < 4; ++j) {
              const int row = wr * 64 + m * 16 + fq * 4 + j;
              const size_t t = (size_t)t0 + row;
              u.tr[cl][row] = acc[m][n][j] + bb + __bfloat162float(ident[t * 256 + col]);
            }
        }
      }
      __syncthreads();
      {
        const int cl = tid >> 3, wseg = tid & 7;
        const int c = n0 + chunk * 32 + cl;
        float* dp = outf + (((size_t)bN * 256 + c) * 256 + hN) * 256 + w0 + wseg * 16;
#pragma unroll
        for (int q = 0; q < 4; ++q)
          *(f32x4*)(dp + q * 4) = *(const f32x4*)&u.tr[cl][wseg * 16 + q * 4];
      }
    }
    return;
  }

#pragma unroll
  for (int m = 0; m < 4; ++m) {
#pragma unroll
    for (int n = 0; n < 4; ++n) {
      const int col = n0 + wc * 64 + n * 16 + fr;
#pragma unroll
      for (int j = 0; j < 4; ++j) {
        const int row = wr * 64 + m * 16 + fq * 4 + j;
        const size_t t = (size_t)t0 + row;
        float v = acc[m][n][j] + bias[col];
        if (EPI == 0) {
          outb[t * ldo + col] = __float2bfloat16(v);
        } else {
          const float s = 1.f / (1.f + __expf(-v));
          bf16* p = gate + t * 768 + col;
          *p = __float2bfloat16(s * __bfloat162float(*p));
        }
      }
    }
  }
}

// ---------------- MFMA window attention ----------------
// qkv: [T][768] bf16 (0:256 q_g, 256:512 k_g, 512:768 v). out: [T][256] bf16.
// grid: 4096 windows x 2 head-halves; block 256 = 4 waves; wave = one head.
__global__ void __launch_bounds__(256, 2)
k_attn_mfma(const bf16* __restrict__ qkv, bf16* __restrict__ out) {
  __shared__ char smem[4 * 13824];
  const int tid = threadIdx.x;
  const int wave = tid >> 6, lane = tid & 63;
  const int fr = lane & 15, fq = lane >> 4;
  const int wi = blockIdx.x >> 1;
  const int head = (blockIdx.x & 1) * 4 + wave;
  const int b = wi >> 10, rem = wi & 1023, wh = rem >> 5, ww = rem & 31;
  const size_t tbase = (size_t)b * HWimg + (size_t)(wh * 8) * Wimg + ww * 8;

  short* VT = (short*)(smem + wave * 13824);          // [32 d][72] (64 ktok + pad)
  short* P  = (short*)(smem + wave * 13824 + 4608);   // [64 q][72] (64 ktok + pad)

  auto tok = [&](int i) -> size_t {
    return tbase + (size_t)(i >> 3) * Wimg + (i & 7);
  };

  // Q, K fragments loaded straight from global in MFMA layout.
  s16x8 kf[4], qf[4];
#pragma unroll
  for (int m = 0; m < 4; ++m)
    kf[m] = *(const s16x8*)(qkv + tok(16 * m + fr) * 768 + 256 + head * 32 + fq * 8);
#pragma unroll
  for (int n = 0; n < 4; ++n)
    qf[n] = *(const s16x8*)(qkv + tok(16 * n + fr) * 768 + head * 32 + fq * 8);

  // stage V transposed: VT[d][ktok]
  {
    const bf16* vb = qkv + tok(lane) * 768 + 512 + head * 32;
#pragma unroll
    for (int c = 0; c < 4; ++c) {
      s16x8 v = *(const s16x8*)(vb + c * 8);
#pragma unroll
      for (int e = 0; e < 8; ++e) VT[(c * 8 + e) * 72 + lane] = v[e];
    }
  }

  // S^T = K Q^T : row = ktok, col = qtok
  f32x4 st[4][4] = {};
#pragma unroll
  for (int m = 0; m < 4; ++m)
#pragma unroll
    for (int n = 0; n < 4; ++n)
      st[m][n] = __builtin_amdgcn_mfma_f32_16x16x32_bf16(kf[m], qf[n], st[m][n], 0, 0, 0);

  // softmax over ktok for each q = fr + 16n ; P written unnormalized (bf16)
  const float scale = 0.17677669529663688f;  // 1/sqrt(32)
  float invs[4];
#pragma unroll
  for (int n = 0; n < 4; ++n) {
    float mx = -1e30f;
#pragma unroll
    for (int m = 0; m < 4; ++m)
#pragma unroll
      for (int j = 0; j < 4; ++j) mx = fmaxf(mx, st[m][n][j]);
    mx = fmaxf(mx, __shfl_xor(mx, 16));
    mx = fmaxf(mx, __shfl_xor(mx, 32));
    float sum = 0.f;
#pragma unroll
    for (int m = 0; m < 4; ++m) {
      s16x4 pk;
#pragma unroll
      for (int j = 0; j < 4; ++j) {
        float e = __expf((st[m][n][j] - mx) * scale);
        sum += e;
        pk[j] = (short)f2u(e);
      }
      *(s16x4*)(P + (fr + 16 * n) * 72 + 16 * m + 4 * fq) = pk;
    }
    sum += __shfl_xor(sum, 16);
    sum += __shfl_xor(sum, 32);
    invs[n] = 1.f / sum;
  }
  __syncthreads();

  // O = P V : row = q, col = d
  f32x4 oc[4][2] = {};
#pragma unroll
  for (int ks = 0; ks < 2; ++ks) {
    s16x8 pf[4], vf[2];
#pragma unroll
    for (int m = 0; m < 4; ++m)
      pf[m] = *(const s16x8*)(P + (fr + 16 * m) * 72 + ks * 32 + fq * 8);
#pragma unroll
    for (int n = 0; n < 2; ++n)
      vf[n] = *(const s16x8*)(VT + (fr + 16 * n) * 72 + ks * 32 + fq * 8);
#pragma unroll
    for (int m = 0; m < 4; ++m)
#pragma unroll
      for (int n = 0; n < 2; ++n)
        oc[m][n] = __builtin_amdgcn_mfma_f32_16x16x32_bf16(pf[m], vf[n], oc[m][n], 0, 0, 0);
  }

#pragma unroll
  for (int m = 0; m < 4; ++m)
#pragma unroll
    for (int j = 0; j < 4; ++j) {
      const float inv = __shfl(invs[m], 4 * fq + j);
      bf16* op = out + tok(16 * m + 4 * fq + j) * 256 + head * 32 + fr;
      op[0]  = __float2bfloat16(oc[m][0][j] * inv);
      op[16] = __float2bfloat16(oc[m][1][j] * inv);
    }
}

// ---------------- host ----------------
extern "C" void kernel_launch(void* const* d_in, const int* in_sizes, int n_in,
                              void* d_out, int out_size, void* d_ws, size_t ws_size,
                              hipStream_t stream) {
  const float* xmap    = (const float*)d_in[0];
  const float* xfeat   = (const float*)d_in[1];
  const float* cmap_w  = (const float*)d_in[2];
  const float* cmap_b  = (const float*)d_in[3];
  const float* cfeat_w = (const float*)d_in[4];
  const float* cfeat_b = (const float*)d_in[5];
  const float* qxmap_w = (const float*)d_in[6];
  const float* qxmap_b = (const float*)d_in[7];
  const float* kxmap_w = (const float*)d_in[8];
  const float* kxmap_b = (const float*)d_in[9];
  const float* vxmap_w = (const float*)d_in[10];
  const float* vxmap_b = (const float*)d_in[11];
  const float* qxfeat_w = (const float*)d_in[12];
  const float* qxfeat_b = (const float*)d_in[13];
  const float* kxfeat_w = (const float*)d_in[14];
  const float* kxfeat_b = (const float*)d_in[15];
  const float* proj_w  = (const float*)d_in[16];
  const float* proj_b  = (const float*)d_in[17];
  const float* cout_w  = (const float*)d_in[18];
  const float* cout_b  = (const float*)d_in[19];

  uint8_t* ws = (uint8_t*)d_ws;
  size_t off = 0;
  auto alloc = [&](size_t bytes) -> void* {
    void* p = ws + off;
    off += (bytes + 255) & ~(size_t)255;
    return p;
  };
  float* zp       = (float*)alloc(4096);
  bf16* cmap_wT   = (bf16*)alloc((size_t)2304 * 256 * 2);
  bf16* cout_wT   = (bf16*)alloc((size_t)2304 * 256 * 2);
  bf16* cfeat_wT  = (bf16*)alloc((size_t)288 * 256 * 2);
  bf16* lin_qkv_wT= (bf16*)alloc((size_t)768 * 256 * 2);
  bf16* lin_f_wT  = (bf16*)alloc((size_t)512 * 256 * 2);
  bf16* proj_wT   = (bf16*)alloc((size_t)256 * 256 * 2);
  float* bias_qkv = (float*)alloc(768 * 4);
  float* bias_f   = (float*)alloc(512 * 4);
  bf16* xm_nhwc   = (bf16*)alloc((size_t)Ttok * 256 * 2);
  bf16* xf_nhwc   = (bf16*)alloc((size_t)Ttok * 32 * 2);
  bf16* xc        = (bf16*)alloc((size_t)Ttok * 256 * 2);
  bf16* fc        = (bf16*)alloc((size_t)Ttok * 256 * 2);
  bf16* qkv       = (bf16*)alloc((size_t)Ttok * 768 * 2);
  bf16* attn_out  = xm_nhwc;          // reuse
  bf16* proj_out  = fc;               // reuse
  bf16* zpb = (bf16*)zp;

  k_zero4k<<<4, 256, 0, stream>>>(zp);
  k_permconv<<<(256 * 9 * 256 + 255) / 256, 256, 0, stream>>>(cmap_w, cmap_wT, 256);
  k_permconv<<<(256 * 9 * 256 + 255) / 256, 256, 0, stream>>>(cout_w, cout_wT, 256);
  k_permconv<<<(256 * 9 * 32 + 255) / 256, 256, 0, stream>>>(cfeat_w, cfeat_wT, 32);
  k_castf2b<<<256, 256, 0, stream>>>(qxmap_w, lin_qkv_wT, 65536);
  k_castf2b<<<256, 256, 0, stream>>>(kxmap_w, lin_qkv_wT + 65536, 65536);
  k_castf2b<<<256, 256, 0, stream>>>(vxmap_w, lin_qkv_wT + 131072, 65536);
  k_castf2b<<<256, 256, 0, stream>>>(qxfeat_w, lin_f_wT, 65536);
  k_castf2b<<<256, 256, 0, stream>>>(kxfeat_w, lin_f_wT + 65536, 65536);
  k_castf2b<<<256, 256, 0, stream>>>(proj_w, proj_wT, 65536);
  k_copyf<<<1, 256, 0, stream>>>(qxmap_b, bias_qkv, 256);
  k_copyf<<<1, 256, 0, stream>>>(kxmap_b, bias_qkv + 256, 256);
  k_copyf<<<1, 256, 0, stream>>>(vxmap_b, bias_qkv + 512, 256);
  k_copyf<<<1, 256, 0, stream>>>(qxfeat_b, bias_f, 256);
  k_copyf<<<1, 256, 0, stream>>>(kxfeat_b, bias_f + 256, 256);

  k_tohwc<<<dim3(Bimg * Himg, Wimg / 32, 256 / 32), 256, 0, stream>>>(xmap, xm_nhwc, 256);
  k_tohwc<<<dim3(Bimg * Himg, Wimg / 32, 1), 256, 0, stream>>>(xfeat, xf_nhwc, 32);

  dim3 blk(256);
  // conv cmap -> xc (identity, bf16)
  k_gemm<256, 9, 0><<<dim3(Ttok / 128, 2), blk, 0, stream>>>(
      xm_nhwc, cmap_wT, cmap_b, xc, 256, nullptr, nullptr, nullptr, zpb);
  // conv cfeat -> fc
  k_gemm<32, 9, 0><<<dim3(Ttok / 128, 2), blk, 0, stream>>>(
      xf_nhwc, cfeat_wT, cfeat_b, fc, 256, nullptr, nullptr, nullptr, zpb);
  // qm|km|vm GEMM -> qkv
  k_gemm<256, 1, 0><<<dim3(Ttok / 128, 6), blk, 0, stream>>>(
      xc, lin_qkv_wT, bias_qkv, qkv, 768, nullptr, nullptr, nullptr, zpb);
  // qf|kf GEMM + sigmoid gating in-place on qkv
  k_gemm<256, 1, 1><<<dim3(Ttok / 128, 4), blk, 0, stream>>>(
      fc, lin_f_wT, bias_f, nullptr, 0, nullptr, nullptr, qkv, zpb);
  // MFMA window attention
  k_attn_mfma<<<dim3(4096 * 2), blk, 0, stream>>>(qkv, attn_out);
  // proj GEMM
  k_gemm<256, 1, 0><<<dim3(Ttok / 128, 2), blk, 0, stream>>>(
      attn_out, proj_wT, proj_b, proj_out, 256, nullptr, nullptr, nullptr, zpb);
  // conv cout + bias + identity -> NCHW fp32 d_out directly
  k_gemm<256, 9, 2><<<dim3(Ttok / 128, 2), blk, 0, stream>>>(
      proj_out, cout_wT, cout_b, nullptr, 0, (float*)d_out, xc, nullptr, zpb);
}

// Round 3
// 1831.275 us; speedup vs baseline: 1.8265x; 1.8265x over previous
//
#include <hip/hip_runtime.h>
#include <hip/hip_bf16.h>
#include <cstdint>
#include <math.h>

using bf16 = __hip_bfloat16;
typedef __attribute__((ext_vector_type(4))) float f32x4;
typedef __attribute__((ext_vector_type(8))) short s16x8;
typedef __attribute__((ext_vector_type(4))) short s16x4;

#define AS3(p) ((__attribute__((address_space(3))) void *)(p))
#define AS1(p) ((const __attribute__((address_space(1))) void *)(p))

static constexpr int Himg = 256, Wimg = 256, Bimg = 4;
static constexpr int HWimg = Himg * Wimg;
static constexpr int Ttok = Bimg * HWimg;   // 262144 tokens

__device__ __forceinline__ void gld16(bf16* lds, const bf16* g) {
  __builtin_amdgcn_global_load_lds(AS1(g), AS3(lds), 16, 0, 0);
}

__device__ __forceinline__ unsigned short f2u(float f) {
  bf16 b = __float2bfloat16(f);
  unsigned short u; __builtin_memcpy(&u, &b, 2); return u;
}

// XCD-chunked remap: hw round-robin (bid%8) -> contiguous logical chunks,
// column tiles innermost so same-A blocks are L2-co-resident on one XCD.
__device__ __forceinline__ void remap_tile(int bid, int total, int NY, int& t0, int& n0) {
  int lin = (bid & 7) * (total >> 3) + (bid >> 3);
  t0 = (lin / NY) * 128;
  n0 = (lin % NY) * 128;
}

// ---------------- prep kernels ----------------
__global__ void k_zero4k(float* p) {
  p[blockIdx.x * 256 + threadIdx.x] = 0.f;
}

__global__ void k_castf2b(const float* __restrict__ s, bf16* __restrict__ d, int n) {
  int i = blockIdx.x * 256 + threadIdx.x;
  if (i < n) d[i] = __float2bfloat16(s[i]);
}

__global__ void k_copyf(const float* __restrict__ s, float* __restrict__ d, int n) {
  int i = blockIdx.x * 256 + threadIdx.x;
  if (i < n) d[i] = s[i];
}

// conv weight permute: OIHW fp32 -> [O][tap][I] bf16
__global__ void k_permconv(const float* __restrict__ w, bf16* __restrict__ o, int I) {
  int idx = blockIdx.x * 256 + threadIdx.x;
  int tot = 256 * 9 * I;
  if (idx >= tot) return;
  int i   = idx % I;
  int rem = idx / I;
  int tap = rem % 9;
  int oc  = rem / 9;
  o[idx] = __float2bfloat16(w[(oc * I + i) * 9 + tap]);
}

// NCHW fp32 -> NHWC bf16
__global__ void k_tohwc(const float* __restrict__ src, bf16* __restrict__ dst, int C) {
  int bh = blockIdx.x;
  int w0 = blockIdx.y * 32;
  int c0 = blockIdx.z * 32;
  int b = bh / Himg, h = bh % Himg;
  __shared__ float tile[32][33];
  int tid = threadIdx.x;
  int x = tid & 31, y = tid >> 5;
  const float* sp = src + (size_t)b * C * HWimg + (size_t)h * Wimg;
#pragma unroll
  for (int p = 0; p < 4; ++p) {
    int cl = y + p * 8;
    tile[cl][x] = sp[(size_t)(c0 + cl) * HWimg + w0 + x];
  }
  __syncthreads();
#pragma unroll
  for (int p = 0; p < 4; ++p) {
    int wl = y + p * 8;
    dst[((size_t)bh * Wimg + w0 + wl) * C + c0 + x] = __float2bfloat16(tile[x][wl]);
  }
}

// NHWC fp32 -> NCHW fp32 (final output)
__global__ void k_tochw(const float* __restrict__ src, float* __restrict__ dst) {
  int bh = blockIdx.x, w0 = blockIdx.y * 32, c0 = blockIdx.z * 32;
  int b = bh >> 8, h = bh & 255;
  __shared__ float tile[32][33];
  int tid = threadIdx.x, x = tid & 31, y = tid >> 5;
  const float* sp = src + (size_t)bh * Wimg * 256;
#pragma unroll
  for (int p = 0; p < 4; ++p) {
    int wl = y + p * 8;
    tile[wl][x] = sp[(size_t)(w0 + wl) * 256 + c0 + x];
  }
  __syncthreads();
#pragma unroll
  for (int p = 0; p < 4; ++p) {
    int cl = y + p * 8;
    dst[(((size_t)b * 256 + c0 + cl) * Himg + h) * Wimg + w0 + x] = tile[x][cl];
  }
}

// ---------------- implicit-GEMM / conv kernel ----------------
// EPI 0: outb[t*ldo+col] = bf16(acc+bias)
// EPI 2: outf[t*256+col] = acc + bias + float(ident[t*256+col])   (NHWC fp32)
template <int CIN, int TAPS, int EPI>
__global__ void __launch_bounds__(256, 2)
k_gemm(const bf16* __restrict__ Ain, const bf16* __restrict__ BT,
       const float* __restrict__ bias,
       bf16* __restrict__ outb, int ldo,
       float* __restrict__ outf, const bf16* __restrict__ ident,
       const bf16* __restrict__ zp, int NY)
{
  constexpr int KTOT = TAPS * CIN;
  int t0, n0;
  remap_tile(blockIdx.x, gridDim.x, NY, t0, n0);
  const int tid = threadIdx.x;
  const int wave = tid >> 6, lane = tid & 63;
  const int seg = lane & 3;
  const int rr  = lane >> 2;

  __shared__ bf16 sA[128 * 32];
  __shared__ bf16 sB[128 * 32];

  f32x4 acc[4][4] = {};

  const int wr = wave >> 1, wc = wave & 1;
  const int fr = lane & 15, fq = lane >> 4;

  for (int k0 = 0; k0 < KTOT; k0 += 32) {
    const int tap = k0 / CIN;
    const int c0  = k0 - tap * CIN;
    const int dy  = tap / 3 - 1, dx = tap % 3 - 1;
#pragma unroll
    for (int i = 0; i < 2; ++i) {
      const int r = wave * 32 + i * 16 + rr;
      const int t = t0 + r;
      const bf16* src;
      if (TAPS == 1) {
        src = Ain + (size_t)t * CIN + c0 + seg * 8;
      } else {
        const int h = (t >> 8) & 255, w = t & 255;
        const int hh = h + dy, ww = w + dx;
        const bool valid = ((unsigned)hh < 256u) && ((unsigned)ww < 256u);
        const long gi = (long)t + dy * Wimg + dx;
        src = valid ? (Ain + gi * CIN + c0 + seg * 8) : (zp + seg * 8);
      }
      gld16(sA + (wave * 32 + i * 16) * 32, src);
    }
#pragma unroll
    for (int i = 0; i < 2; ++i) {
      const int r = wave * 32 + i * 16 + rr;
      const bf16* src = BT + (size_t)(n0 + r) * KTOT + k0 + seg * 8;
      gld16(sB + (wave * 32 + i * 16) * 32, src);
    }
    __syncthreads();
    s16x8 af[4], bfrag[4];
#pragma unroll
    for (int m = 0; m < 4; ++m)
      af[m] = *(const s16x8*)(sA + (wr * 64 + m * 16 + fr) * 32 + fq * 8);
#pragma unroll
    for (int n = 0; n < 4; ++n)
      bfrag[n] = *(const s16x8*)(sB + (wc * 64 + n * 16 + fr) * 32 + fq * 8);
#pragma unroll
    for (int m = 0; m < 4; ++m)
#pragma unroll
      for (int n = 0; n < 4; ++n)
        acc[m][n] = __builtin_amdgcn_mfma_f32_16x16x32_bf16(af[m], bfrag[n], acc[m][n], 0, 0, 0);
    __syncthreads();
  }

#pragma unroll
  for (int m = 0; m < 4; ++m) {
#pragma unroll
    for (int n = 0; n < 4; ++n) {
      const int col = n0 + wc * 64 + n * 16 + fr;
#pragma unroll
      for (int j = 0; j < 4; ++j) {
        const int row = wr * 64 + m * 16 + fq * 4 + j;
        const size_t t = (size_t)t0 + row;
        float v = acc[m][n][j] + bias[col];
        if (EPI == 0) {
          outb[t * ldo + col] = __float2bfloat16(v);
        } else {
          v += __bfloat162float(ident[t * 256 + col]);
          outf[t * 256 + col] = v;
        }
      }
    }
  }
}

// ---------------- fused dual GEMM: qkv = (linear_m) gated by sigmoid(linear_f) ----------------
// out[t*768+col] = (accm+bm[col]) * (col<512 ? sigmoid(accf+bf[col]) : 1)
__global__ void __launch_bounds__(256, 2)
k_gemm_qkv(const bf16* __restrict__ Am, const bf16* __restrict__ Af,
           const bf16* __restrict__ Bm, const bf16* __restrict__ Bf,
           const float* __restrict__ bm, const float* __restrict__ bfi,
           bf16* __restrict__ out)
{
  int t0, n0;
  remap_tile(blockIdx.x, gridDim.x, 6, t0, n0);
  const bool gated = n0 < 512;
  const int tid = threadIdx.x;
  const int wave = tid >> 6, lane = tid & 63;
  const int seg = lane & 3;
  const int rr  = lane >> 2;

  __shared__ bf16 sAm[128 * 32];
  __shared__ bf16 sBm[128 * 32];
  __shared__ bf16 sAf[128 * 32];
  __shared__ bf16 sBf[128 * 32];

  f32x4 accm[4][4] = {};
  f32x4 accf[4][4] = {};

  const int wr = wave >> 1, wc = wave & 1;
  const int fr = lane & 15, fq = lane >> 4;

  for (int k0 = 0; k0 < 256; k0 += 32) {
#pragma unroll
    for (int i = 0; i < 2; ++i) {
      const int r = wave * 32 + i * 16 + rr;
      gld16(sAm + (wave * 32 + i * 16) * 32, Am + (size_t)(t0 + r) * 256 + k0 + seg * 8);
      gld16(sBm + (wave * 32 + i * 16) * 32, Bm + (size_t)(n0 + r) * 256 + k0 + seg * 8);
      if (gated) {
        gld16(sAf + (wave * 32 + i * 16) * 32, Af + (size_t)(t0 + r) * 256 + k0 + seg * 8);
        gld16(sBf + (wave * 32 + i * 16) * 32, Bf + (size_t)(n0 + r) * 256 + k0 + seg * 8);
      }
    }
    __syncthreads();
    s16x8 am[4], bmf[4];
#pragma unroll
    for (int m = 0; m < 4; ++m)
      am[m] = *(const s16x8*)(sAm + (wr * 64 + m * 16 + fr) * 32 + fq * 8);
#pragma unroll
    for (int n = 0; n < 4; ++n)
      bmf[n] = *(const s16x8*)(sBm + (wc * 64 + n * 16 + fr) * 32 + fq * 8);
#pragma unroll
    for (int m = 0; m < 4; ++m)
#pragma unroll
      for (int n = 0; n < 4; ++n)
        accm[m][n] = __builtin_amdgcn_mfma_f32_16x16x32_bf16(am[m], bmf[n], accm[m][n], 0, 0, 0);
    if (gated) {
      s16x8 af[4], bff[4];
#pragma unroll
      for (int m = 0; m < 4; ++m)
        af[m] = *(const s16x8*)(sAf + (wr * 64 + m * 16 + fr) * 32 + fq * 8);
#pragma unroll
      for (int n = 0; n < 4; ++n)
        bff[n] = *(const s16x8*)(sBf + (wc * 64 + n * 16 + fr) * 32 + fq * 8);
#pragma unroll
      for (int m = 0; m < 4; ++m)
#pragma unroll
        for (int n = 0; n < 4; ++n)
          accf[m][n] = __builtin_amdgcn_mfma_f32_16x16x32_bf16(af[m], bff[n], accf[m][n], 0, 0, 0);
    }
    __syncthreads();
  }

#pragma unroll
  for (int m = 0; m < 4; ++m) {
#pragma unroll
    for (int n = 0; n < 4; ++n) {
      const int col = n0 + wc * 64 + n * 16 + fr;
#pragma unroll
      for (int j = 0; j < 4; ++j) {
        const int row = wr * 64 + m * 16 + fq * 4 + j;
        const size_t t = (size_t)t0 + row;
        float v = accm[m][n][j] + bm[col];
        if (gated) {
          const float g = accf[m][n][j] + bfi[col];
          v *= 1.f / (1.f + __expf(-g));
        }
        out[t * 768 + col] = __float2bfloat16(v);
      }
    }
  }
}

// ---------------- MFMA window attention (coalesced LDS staging) ----------------
// qkv: [T][768] bf16 (0:256 q_g, 256:512 k_g, 512:768 v). out: [T][256] bf16.
// grid: 4096 windows x 2 head-halves; block 256 = 4 waves; wave = one head.
// All LDS regions are wave-private -> no __syncthreads needed.
__global__ void __launch_bounds__(256, 2)
k_attn_mfma(const bf16* __restrict__ qkv, bf16* __restrict__ out) {
  __shared__ short smem[4 * 7424];   // 14848 B per wave
  const int tid = threadIdx.x;
  const int wave = tid >> 6, lane = tid & 63;
  const int fr = lane & 15, fq = lane >> 4;
  const int wi = blockIdx.x >> 1;
  const int head = (blockIdx.x & 1) * 4 + wave;
  const int b = wi >> 10, rem = wi & 1023, wh = rem >> 5, ww = rem & 31;
  const size_t tbase = (size_t)b * HWimg + (size_t)(wh * 8) * Wimg + ww * 8;

  short* Qs = smem + wave * 7424;     // [64][40] shorts
  short* Ks = Qs + 2560;              // [64][40]
  short* VT = Qs + 5120;              // [32][72]
  short* P  = Qs;                     // [64][72]  (alias over Qs+Ks after frags read)
  short* Ol = Qs;                     // [64][40]  (alias over P after P reads)

  auto tok = [&](int i) -> size_t {
    return tbase + (size_t)(i >> 3) * Wimg + (i & 7);
  };

  // coalesced staging: each lane loads its token's contiguous 64B head-slices
  {
    const bf16* tb = qkv + tok(lane) * 768 + head * 32;
#pragma unroll
    for (int c = 0; c < 4; ++c) {
      s16x8 qv = *(const s16x8*)(tb + c * 8);
      s16x8 kv = *(const s16x8*)(tb + 256 + c * 8);
      s16x8 vv = *(const s16x8*)(tb + 512 + c * 8);
      *(s16x8*)(Qs + lane * 40 + c * 8) = qv;
      *(s16x8*)(Ks + lane * 40 + c * 8) = kv;
#pragma unroll
      for (int e = 0; e < 8; ++e) VT[(c * 8 + e) * 72 + lane] = vv[e];
    }
  }

  // fragments (wave-private LDS; compiler inserts lgkmcnt)
  s16x8 kf[4], qf[4];
#pragma unroll
  for (int m = 0; m < 4; ++m)
    kf[m] = *(const s16x8*)(Ks + (fr + 16 * m) * 40 + fq * 8);
#pragma unroll
  for (int n = 0; n < 4; ++n)
    qf[n] = *(const s16x8*)(Qs + (fr + 16 * n) * 40 + fq * 8);

  // S^T = K Q^T : row = ktok, col = qtok
  f32x4 st[4][4] = {};
#pragma unroll
  for (int m = 0; m < 4; ++m)
#pragma unroll
    for (int n = 0; n < 4; ++n)
      st[m][n] = __builtin_amdgcn_mfma_f32_16x16x32_bf16(kf[m], qf[n], st[m][n], 0, 0, 0);

  // softmax over ktok for each q = fr + 16n; P written unnormalized (bf16)
  const float scale = 0.17677669529663688f;  // 1/sqrt(32)
  float invs[4];
#pragma unroll
  for (int n = 0; n < 4; ++n) {
    float mx = -1e30f;
#pragma unroll
    for (int m = 0; m < 4; ++m)
#pragma unroll
      for (int j = 0; j < 4; ++j) mx = fmaxf(mx, st[m][n][j]);
    mx = fmaxf(mx, __shfl_xor(mx, 16));
    mx = fmaxf(mx, __shfl_xor(mx, 32));
    float sum = 0.f;
#pragma unroll
    for (int m = 0; m < 4; ++m) {
      s16x4 pk;
#pragma unroll
      for (int j = 0; j < 4; ++j) {
        float e = __expf((st[m][n][j] - mx) * scale);
        sum += e;
        pk[j] = (short)f2u(e);
      }
      *(s16x4*)(P + (fr + 16 * n) * 72 + 16 * m + 4 * fq) = pk;
    }
    sum += __shfl_xor(sum, 16);
    sum += __shfl_xor(sum, 32);
    invs[n] = 1.f / sum;
  }

  // O = P V : row = q, col = d
  f32x4 oc[4][2] = {};
#pragma unroll
  for (int ks = 0; ks < 2; ++ks) {
    s16x8 pf[4], vf[2];
#pragma unroll
    for (int m = 0; m < 4; ++m)
      pf[m] = *(const s16x8*)(P + (fr + 16 * m) * 72 + ks * 32 + fq * 8);
#pragma unroll
    for (int n = 0; n < 2; ++n)
      vf[n] = *(const s16x8*)(VT + (fr + 16 * n) * 72 + ks * 32 + fq * 8);
#pragma unroll
    for (int m = 0; m < 4; ++m)
#pragma unroll
      for (int n = 0; n < 2; ++n)
        oc[m][n] = __builtin_amdgcn_mfma_f32_16x16x32_bf16(pf[m], vf[n], oc[m][n], 0, 0, 0);
  }

  // normalize, transpose through LDS, store 64B/lane coalesced
#pragma unroll
  for (int m = 0; m < 4; ++m)
#pragma unroll
    for (int j = 0; j < 4; ++j) {
      const float inv = __shfl(invs[m], 4 * fq + j);
      const int q = 16 * m + 4 * fq + j;
#pragma unroll
      for (int n = 0; n < 2; ++n)
        Ol[q * 40 + fr + 16 * n] = (short)f2u(oc[m][n][j] * inv);
    }
  {
    bf16* op = out + tok(lane) * 256 + head * 32;
#pragma unroll
    for (int c = 0; c < 4; ++c)
      *(s16x8*)(op + c * 8) = *(const s16x8*)(Ol + lane * 40 + c * 8);
  }
}

// ---------------- host ----------------
extern "C" void kernel_launch(void* const* d_in, const int* in_sizes, int n_in,
                              void* d_out, int out_size, void* d_ws, size_t ws_size,
                              hipStream_t stream) {
  const float* xmap    = (const float*)d_in[0];
  const float* xfeat   = (const float*)d_in[1];
  const float* cmap_w  = (const float*)d_in[2];
  const float* cmap_b  = (const float*)d_in[3];
  const float* cfeat_w = (const float*)d_in[4];
  const float* cfeat_b = (const float*)d_in[5];
  const float* qxmap_w = (const float*)d_in[6];
  const float* qxmap_b = (const float*)d_in[7];
  const float* kxmap_w = (const float*)d_in[8];
  const float* kxmap_b = (const float*)d_in[9];
  const float* vxmap_w = (const float*)d_in[10];
  const float* vxmap_b = (const float*)d_in[11];
  const float* qxfeat_w = (const float*)d_in[12];
  const float* qxfeat_b = (const float*)d_in[13];
  const float* kxfeat_w = (const float*)d_in[14];
  const float* kxfeat_b = (const float*)d_in[15];
  const float* proj_w  = (const float*)d_in[16];
  const float* proj_b  = (const float*)d_in[17];
  const float* cout_w  = (const float*)d_in[18];
  const float* cout_b  = (const float*)d_in[19];

  uint8_t* ws = (uint8_t*)d_ws;
  size_t off = 0;
  auto alloc = [&](size_t bytes) -> void* {
    void* p = ws + off;
    off += (bytes + 255) & ~(size_t)255;
    return p;
  };
  float* zp       = (float*)alloc(4096);
  bf16* cmap_wT   = (bf16*)alloc((size_t)2304 * 256 * 2);
  bf16* cout_wT   = (bf16*)alloc((size_t)2304 * 256 * 2);
  bf16* cfeat_wT  = (bf16*)alloc((size_t)288 * 256 * 2);
  bf16* lin_qkv_wT= (bf16*)alloc((size_t)768 * 256 * 2);
  bf16* lin_f_wT  = (bf16*)alloc((size_t)512 * 256 * 2);
  bf16* proj_wT   = (bf16*)alloc((size_t)256 * 256 * 2);
  float* bias_qkv = (float*)alloc(768 * 4);
  float* bias_f   = (float*)alloc(512 * 4);
  bf16* xm_nhwc   = (bf16*)alloc((size_t)Ttok * 256 * 2);
  bf16* xf_nhwc   = (bf16*)alloc((size_t)Ttok * 32 * 2);
  bf16* xc        = (bf16*)alloc((size_t)Ttok * 256 * 2);
  bf16* fc        = (bf16*)alloc((size_t)Ttok * 256 * 2);
  bf16* qkv       = (bf16*)alloc((size_t)Ttok * 768 * 2);
  bf16* attn_out  = xm_nhwc;          // reuse (dead after cmap conv)
  bf16* proj_out  = fc;               // reuse (dead after qkv dual GEMM)
  float* convout  = (float*)qkv;      // reuse (dead after attention)
  bf16* zpb = (bf16*)zp;

  k_zero4k<<<4, 256, 0, stream>>>(zp);
  k_permconv<<<(256 * 9 * 256 + 255) / 256, 256, 0, stream>>>(cmap_w, cmap_wT, 256);
  k_permconv<<<(256 * 9 * 256 + 255) / 256, 256, 0, stream>>>(cout_w, cout_wT, 256);
  k_permconv<<<(256 * 9 * 32 + 255) / 256, 256, 0, stream>>>(cfeat_w, cfeat_wT, 32);
  k_castf2b<<<256, 256, 0, stream>>>(qxmap_w, lin_qkv_wT, 65536);
  k_castf2b<<<256, 256, 0, stream>>>(kxmap_w, lin_qkv_wT + 65536, 65536);
  k_castf2b<<<256, 256, 0, stream>>>(vxmap_w, lin_qkv_wT + 131072, 65536);
  k_castf2b<<<256, 256, 0, stream>>>(qxfeat_w, lin_f_wT, 65536);
  k_castf2b<<<256, 256, 0, stream>>>(kxfeat_w, lin_f_wT + 65536, 65536);
  k_castf2b<<<256, 256, 0, stream>>>(proj_w, proj_wT, 65536);
  k_copyf<<<1, 256, 0, stream>>>(qxmap_b, bias_qkv, 256);
  k_copyf<<<1, 256, 0, stream>>>(kxmap_b, bias_qkv + 256, 256);
  k_copyf<<<1, 256, 0, stream>>>(vxmap_b, bias_qkv + 512, 256);
  k_copyf<<<1, 256, 0, stream>>>(qxfeat_b, bias_f, 256);
  k_copyf<<<1, 256, 0, stream>>>(kxfeat_b, bias_f + 256, 256);

  k_tohwc<<<dim3(Bimg * Himg, Wimg / 32, 256 / 32), 256, 0, stream>>>(xmap, xm_nhwc, 256);
  k_tohwc<<<dim3(Bimg * Himg, Wimg / 32, 1), 256, 0, stream>>>(xfeat, xf_nhwc, 32);

  dim3 blk(256);
  const int NT = Ttok / 128;   // 2048 row tiles
  // conv cmap -> xc
  k_gemm<256, 9, 0><<<dim3(NT * 2), blk, 0, stream>>>(
      xm_nhwc, cmap_wT, cmap_b, xc, 256, nullptr, nullptr, zpb, 2);
  // conv cfeat -> fc
  k_gemm<32, 9, 0><<<dim3(NT * 2), blk, 0, stream>>>(
      xf_nhwc, cfeat_wT, cfeat_b, fc, 256, nullptr, nullptr, zpb, 2);
  // fused dual GEMM: qkv (q,k gated by sigmoid of feat-linear)
  k_gemm_qkv<<<dim3(NT * 6), blk, 0, stream>>>(
      xc, fc, lin_qkv_wT, lin_f_wT, bias_qkv, bias_f, qkv);
  // MFMA window attention
  k_attn_mfma<<<dim3(4096 * 2), blk, 0, stream>>>(qkv, attn_out);
  // proj GEMM
  k_gemm<256, 1, 0><<<dim3(NT * 2), blk, 0, stream>>>(
      attn_out, proj_wT, proj_b, proj_out, 256, nullptr, nullptr, zpb, 2);
  // conv cout + bias + identity -> convout (NHWC fp32)
  k_gemm<256, 9, 2><<<dim3(NT * 2), blk, 0, stream>>>(
      proj_out, cout_wT, cout_b, nullptr, 0, convout, xc, zpb, 2);
  // NHWC -> NCHW final
  k_tochw<<<dim3(Bimg * Himg, Wimg / 32, 256 / 32), 256, 0, stream>>>(convout, (float*)d_out);
}

// Round 4
// 1788.607 us; speedup vs baseline: 1.8701x; 1.0239x over previous
//
#include <hip/hip_runtime.h>
#include <hip/hip_bf16.h>
#include <cstdint>
#include <math.h>

using bf16 = __hip_bfloat16;
typedef __attribute__((ext_vector_type(4))) float f32x4;
typedef __attribute__((ext_vector_type(8))) short s16x8;
typedef __attribute__((ext_vector_type(4))) short s16x4;

#define AS3(p) ((__attribute__((address_space(3))) void *)(p))
#define AS1(p) ((const __attribute__((address_space(1))) void *)(p))

static constexpr int Himg = 256, Wimg = 256, Bimg = 4;
static constexpr int HWimg = Himg * Wimg;
static constexpr int Ttok = Bimg * HWimg;   // 262144 tokens

__device__ __forceinline__ void gld16(bf16* lds, const bf16* g) {
  __builtin_amdgcn_global_load_lds(AS1(g), AS3(lds), 16, 0, 0);
}

__device__ __forceinline__ unsigned short f2u(float f) {
  bf16 b = __float2bfloat16(f);
  unsigned short u; __builtin_memcpy(&u, &b, 2); return u;
}

// XCD-chunked remap: hw round-robin (bid%8) -> contiguous logical chunks,
// column tiles innermost so same-A blocks are L2-co-resident on one XCD.
__device__ __forceinline__ void remap_tile(int bid, int total, int NY, int& t0, int& n0) {
  int lin = (bid & 7) * (total >> 3) + (bid >> 3);
  t0 = (lin / NY) * 128;
  n0 = (lin % NY) * 128;
}

// ---------------- prep kernels ----------------
__global__ void k_zero4k(float* p) {
  p[blockIdx.x * 256 + threadIdx.x] = 0.f;
}

__global__ void k_castf2b(const float* __restrict__ s, bf16* __restrict__ d, int n) {
  int i = blockIdx.x * 256 + threadIdx.x;
  if (i < n) d[i] = __float2bfloat16(s[i]);
}

__global__ void k_copyf(const float* __restrict__ s, float* __restrict__ d, int n) {
  int i = blockIdx.x * 256 + threadIdx.x;
  if (i < n) d[i] = s[i];
}

// conv weight permute: OIHW fp32 -> [O][tap][I] bf16
__global__ void k_permconv(const float* __restrict__ w, bf16* __restrict__ o, int I) {
  int idx = blockIdx.x * 256 + threadIdx.x;
  int tot = 256 * 9 * I;
  if (idx >= tot) return;
  int i   = idx % I;
  int rem = idx / I;
  int tap = rem % 9;
  int oc  = rem / 9;
  o[idx] = __float2bfloat16(w[(oc * I + i) * 9 + tap]);
}

// NCHW fp32 -> NHWC bf16
__global__ void k_tohwc(const float* __restrict__ src, bf16* __restrict__ dst, int C) {
  int bh = blockIdx.x;
  int w0 = blockIdx.y * 32;
  int c0 = blockIdx.z * 32;
  int b = bh / Himg, h = bh % Himg;
  __shared__ float tile[32][33];
  int tid = threadIdx.x;
  int x = tid & 31, y = tid >> 5;
  const float* sp = src + (size_t)b * C * HWimg + (size_t)h * Wimg;
#pragma unroll
  for (int p = 0; p < 4; ++p) {
    int cl = y + p * 8;
    tile[cl][x] = sp[(size_t)(c0 + cl) * HWimg + w0 + x];
  }
  __syncthreads();
#pragma unroll
  for (int p = 0; p < 4; ++p) {
    int wl = y + p * 8;
    dst[((size_t)bh * Wimg + w0 + wl) * C + c0 + x] = __float2bfloat16(tile[x][wl]);
  }
}

// NHWC fp32 -> NCHW fp32 (final output)
__global__ void k_tochw(const float* __restrict__ src, float* __restrict__ dst) {
  int bh = blockIdx.x, w0 = blockIdx.y * 32, c0 = blockIdx.z * 32;
  int b = bh >> 8, h = bh & 255;
  __shared__ float tile[32][33];
  int tid = threadIdx.x, x = tid & 31, y = tid >> 5;
  const float* sp = src + (size_t)bh * Wimg * 256;
#pragma unroll
  for (int p = 0; p < 4; ++p) {
    int wl = y + p * 8;
    tile[wl][x] = sp[(size_t)(w0 + wl) * 256 + c0 + x];
  }
  __syncthreads();
#pragma unroll
  for (int p = 0; p < 4; ++p) {
    int cl = y + p * 8;
    dst[(((size_t)b * 256 + c0 + cl) * Himg + h) * Wimg + w0 + x] = tile[x][cl];
  }
}

// ---------------- implicit-GEMM / conv kernel (2-phase dbuf pipeline) ----------------
// EPI 0: outb[t*ldo+col] = bf16(acc+bias)
// EPI 2: outf[t*256+col] = acc + bias + float(ident[t*256+col])   (NHWC fp32)
template <int CIN, int TAPS, int EPI>
__global__ void __launch_bounds__(256, 2)
k_gemm(const bf16* __restrict__ Ain, const bf16* __restrict__ BT,
       const float* __restrict__ bias,
       bf16* __restrict__ outb, int ldo,
       float* __restrict__ outf, const bf16* __restrict__ ident,
       const bf16* __restrict__ zp, int NY)
{
  constexpr int KTOT = TAPS * CIN;
  constexpr int NK = KTOT / 32;
  int t0, n0;
  remap_tile(blockIdx.x, gridDim.x, NY, t0, n0);
  const int tid = threadIdx.x;
  const int wave = tid >> 6, lane = tid & 63;
  const int seg = lane & 3;
  const int rr  = lane >> 2;

  __shared__ bf16 sA[2][128 * 32];
  __shared__ bf16 sB[2][128 * 32];

  f32x4 acc[4][4] = {};

  const int wr = wave >> 1, wc = wave & 1;
  const int fr = lane & 15, fq = lane >> 4;

  auto stage = [&](int buf, int k0) {
    const int tap = k0 / CIN;
    const int c0  = k0 - tap * CIN;
    const int dy  = tap / 3 - 1, dx = tap % 3 - 1;
#pragma unroll
    for (int i = 0; i < 2; ++i) {
      const int r = wave * 32 + i * 16 + rr;
      const int t = t0 + r;
      const bf16* src;
      if (TAPS == 1) {
        src = Ain + (size_t)t * CIN + k0 + seg * 8;
      } else {
        const int h = (t >> 8) & 255, w = t & 255;
        const int hh = h + dy, ww = w + dx;
        const bool valid = ((unsigned)hh < 256u) && ((unsigned)ww < 256u);
        const long gi = (long)t + dy * Wimg + dx;
        src = valid ? (Ain + gi * CIN + c0 + seg * 8) : (zp + seg * 8);
      }
      gld16(sA[buf] + (wave * 32 + i * 16) * 32, src);
      gld16(sB[buf] + (wave * 32 + i * 16) * 32,
            BT + (size_t)(n0 + wave * 32 + i * 16 + rr) * KTOT + k0 + seg * 8);
    }
  };

  stage(0, 0);
  __syncthreads();
  for (int ks = 0; ks < NK; ++ks) {
    const int cur = ks & 1;
    if (ks + 1 < NK) stage(cur ^ 1, (ks + 1) * 32);
    s16x8 af[4], bfrag[4];
#pragma unroll
    for (int m = 0; m < 4; ++m)
      af[m] = *(const s16x8*)(sA[cur] + (wr * 64 + m * 16 + fr) * 32 + fq * 8);
#pragma unroll
    for (int n = 0; n < 4; ++n)
      bfrag[n] = *(const s16x8*)(sB[cur] + (wc * 64 + n * 16 + fr) * 32 + fq * 8);
#pragma unroll
    for (int m = 0; m < 4; ++m)
#pragma unroll
      for (int n = 0; n < 4; ++n)
        acc[m][n] = __builtin_amdgcn_mfma_f32_16x16x32_bf16(af[m], bfrag[n], acc[m][n], 0, 0, 0);
    __syncthreads();
  }

#pragma unroll
  for (int m = 0; m < 4; ++m) {
#pragma unroll
    for (int n = 0; n < 4; ++n) {
      const int col = n0 + wc * 64 + n * 16 + fr;
#pragma unroll
      for (int j = 0; j < 4; ++j) {
        const int row = wr * 64 + m * 16 + fq * 4 + j;
        const size_t t = (size_t)t0 + row;
        float v = acc[m][n][j] + bias[col];
        if (EPI == 0) {
          outb[t * ldo + col] = __float2bfloat16(v);
        } else {
          v += __bfloat162float(ident[t * 256 + col]);
          outf[t * 256 + col] = v;
        }
      }
    }
  }
}

// ---------------- gated dual GEMM: out = (A_m B_m + b_m) * sigmoid(A_f B_f + b_f) ----------------
// Flat 16-stage pipeline alternating m/f tiles through the 2-buffer ping-pong.
// Only gated columns (n0 < 512). out: qkv[t*768 + col].
__global__ void __launch_bounds__(256, 2)
k_gemm_qkv(const bf16* __restrict__ Am, const bf16* __restrict__ Af,
           const bf16* __restrict__ Bm, const bf16* __restrict__ Bf,
           const float* __restrict__ bm, const float* __restrict__ bfi,
           bf16* __restrict__ out)
{
  int t0, n0;
  remap_tile(blockIdx.x, gridDim.x, 4, t0, n0);
  const int tid = threadIdx.x;
  const int wave = tid >> 6, lane = tid & 63;
  const int seg = lane & 3;
  const int rr  = lane >> 2;

  __shared__ bf16 sA[2][128 * 32];
  __shared__ bf16 sB[2][128 * 32];

  f32x4 accm[4][4] = {};
  f32x4 accf[4][4] = {};

  const int wr = wave >> 1, wc = wave & 1;
  const int fr = lane & 15, fq = lane >> 4;

  auto stage = [&](int buf, int s) {
    const int k0 = (s >> 1) * 32;
    const bool useF = (s & 1);
    const bf16* A = useF ? Af : Am;
    const bf16* B = useF ? Bf : Bm;
#pragma unroll
    for (int i = 0; i < 2; ++i) {
      const int r = wave * 32 + i * 16 + rr;
      gld16(sA[buf] + (wave * 32 + i * 16) * 32, A + (size_t)(t0 + r) * 256 + k0 + seg * 8);
      gld16(sB[buf] + (wave * 32 + i * 16) * 32, B + (size_t)(n0 + r) * 256 + k0 + seg * 8);
    }
  };

  stage(0, 0);
  __syncthreads();
  for (int s = 0; s < 16; ++s) {
    const int cur = s & 1;
    if (s + 1 < 16) stage(cur ^ 1, s + 1);
    s16x8 af[4], bfrag[4];
#pragma unroll
    for (int m = 0; m < 4; ++m)
      af[m] = *(const s16x8*)(sA[cur] + (wr * 64 + m * 16 + fr) * 32 + fq * 8);
#pragma unroll
    for (int n = 0; n < 4; ++n)
      bfrag[n] = *(const s16x8*)(sB[cur] + (wc * 64 + n * 16 + fr) * 32 + fq * 8);
    if (s & 1) {
#pragma unroll
      for (int m = 0; m < 4; ++m)
#pragma unroll
        for (int n = 0; n < 4; ++n)
          accf[m][n] = __builtin_amdgcn_mfma_f32_16x16x32_bf16(af[m], bfrag[n], accf[m][n], 0, 0, 0);
    } else {
#pragma unroll
      for (int m = 0; m < 4; ++m)
#pragma unroll
        for (int n = 0; n < 4; ++n)
          accm[m][n] = __builtin_amdgcn_mfma_f32_16x16x32_bf16(af[m], bfrag[n], accm[m][n], 0, 0, 0);
    }
    __syncthreads();
  }

#pragma unroll
  for (int m = 0; m < 4; ++m) {
#pragma unroll
    for (int n = 0; n < 4; ++n) {
      const int col = n0 + wc * 64 + n * 16 + fr;
#pragma unroll
      for (int j = 0; j < 4; ++j) {
        const int row = wr * 64 + m * 16 + fq * 4 + j;
        const size_t t = (size_t)t0 + row;
        float v = accm[m][n][j] + bm[col];
        const float g = accf[m][n][j] + bfi[col];
        v *= 1.f / (1.f + __expf(-g));
        out[t * 768 + col] = __float2bfloat16(v);
      }
    }
  }
}

// ---------------- MFMA window attention (coalesced LDS staging) ----------------
__global__ void __launch_bounds__(256, 2)
k_attn_mfma(const bf16* __restrict__ qkv, bf16* __restrict__ out) {
  __shared__ short smem[4 * 7424];   // 14848 B per wave
  const int tid = threadIdx.x;
  const int wave = tid >> 6, lane = tid & 63;
  const int fr = lane & 15, fq = lane >> 4;
  const int wi = blockIdx.x >> 1;
  const int head = (blockIdx.x & 1) * 4 + wave;
  const int b = wi >> 10, rem = wi & 1023, wh = rem >> 5, ww = rem & 31;
  const size_t tbase = (size_t)b * HWimg + (size_t)(wh * 8) * Wimg + ww * 8;

  short* Qs = smem + wave * 7424;     // [64][40]
  short* Ks = Qs + 2560;              // [64][40]
  short* VT = Qs + 5120;              // [32][72]
  short* P  = Qs;                     // [64][72] alias
  short* Ol = Qs;                     // [64][40] alias

  auto tok = [&](int i) -> size_t {
    return tbase + (size_t)(i >> 3) * Wimg + (i & 7);
  };

  {
    const bf16* tb = qkv + tok(lane) * 768 + head * 32;
#pragma unroll
    for (int c = 0; c < 4; ++c) {
      s16x8 qv = *(const s16x8*)(tb + c * 8);
      s16x8 kv = *(const s16x8*)(tb + 256 + c * 8);
      s16x8 vv = *(const s16x8*)(tb + 512 + c * 8);
      *(s16x8*)(Qs + lane * 40 + c * 8) = qv;
      *(s16x8*)(Ks + lane * 40 + c * 8) = kv;
#pragma unroll
      for (int e = 0; e < 8; ++e) VT[(c * 8 + e) * 72 + lane] = vv[e];
    }
  }

  s16x8 kf[4], qf[4];
#pragma unroll
  for (int m = 0; m < 4; ++m)
    kf[m] = *(const s16x8*)(Ks + (fr + 16 * m) * 40 + fq * 8);
#pragma unroll
  for (int n = 0; n < 4; ++n)
    qf[n] = *(const s16x8*)(Qs + (fr + 16 * n) * 40 + fq * 8);

  f32x4 st[4][4] = {};
#pragma unroll
  for (int m = 0; m < 4; ++m)
#pragma unroll
    for (int n = 0; n < 4; ++n)
      st[m][n] = __builtin_amdgcn_mfma_f32_16x16x32_bf16(kf[m], qf[n], st[m][n], 0, 0, 0);

  const float scale = 0.17677669529663688f;  // 1/sqrt(32)
  float invs[4];
#pragma unroll
  for (int n = 0; n < 4; ++n) {
    float mx = -1e30f;
#pragma unroll
    for (int m = 0; m < 4; ++m)
#pragma unroll
      for (int j = 0; j < 4; ++j) mx = fmaxf(mx, st[m][n][j]);
    mx = fmaxf(mx, __shfl_xor(mx, 16));
    mx = fmaxf(mx, __shfl_xor(mx, 32));
    float sum = 0.f;
#pragma unroll
    for (int m = 0; m < 4; ++m) {
      s16x4 pk;
#pragma unroll
      for (int j = 0; j < 4; ++j) {
        float e = __expf((st[m][n][j] - mx) * scale);
        sum += e;
        pk[j] = (short)f2u(e);
      }
      *(s16x4*)(P + (fr + 16 * n) * 72 + 16 * m + 4 * fq) = pk;
    }
    sum += __shfl_xor(sum, 16);
    sum += __shfl_xor(sum, 32);
    invs[n] = 1.f / sum;
  }

  f32x4 oc[4][2] = {};
#pragma unroll
  for (int ks = 0; ks < 2; ++ks) {
    s16x8 pf[4], vf[2];
#pragma unroll
    for (int m = 0; m < 4; ++m)
      pf[m] = *(const s16x8*)(P + (fr + 16 * m) * 72 + ks * 32 + fq * 8);
#pragma unroll
    for (int n = 0; n < 2; ++n)
      vf[n] = *(const s16x8*)(VT + (fr + 16 * n) * 72 + ks * 32 + fq * 8);
#pragma unroll
    for (int m = 0; m < 4; ++m)
#pragma unroll
      for (int n = 0; n < 2; ++n)
        oc[m][n] = __builtin_amdgcn_mfma_f32_16x16x32_bf16(pf[m], vf[n], oc[m][n], 0, 0, 0);
  }

#pragma unroll
  for (int m = 0; m < 4; ++m)
#pragma unroll
    for (int j = 0; j < 4; ++j) {
      const float inv = __shfl(invs[m], 4 * fq + j);
      const int q = 16 * m + 4 * fq + j;
#pragma unroll
      for (int n = 0; n < 2; ++n)
        Ol[q * 40 + fr + 16 * n] = (short)f2u(oc[m][n][j] * inv);
    }
  {
    bf16* op = out + tok(lane) * 256 + head * 32;
#pragma unroll
    for (int c = 0; c < 4; ++c)
      *(s16x8*)(op + c * 8) = *(const s16x8*)(Ol + lane * 40 + c * 8);
  }
}

// ---------------- host ----------------
extern "C" void kernel_launch(void* const* d_in, const int* in_sizes, int n_in,
                              void* d_out, int out_size, void* d_ws, size_t ws_size,
                              hipStream_t stream) {
  const float* xmap    = (const float*)d_in[0];
  const float* xfeat   = (const float*)d_in[1];
  const float* cmap_w  = (const float*)d_in[2];
  const float* cmap_b  = (const float*)d_in[3];
  const float* cfeat_w = (const float*)d_in[4];
  const float* cfeat_b = (const float*)d_in[5];
  const float* qxmap_w = (const float*)d_in[6];
  const float* qxmap_b = (const float*)d_in[7];
  const float* kxmap_w = (const float*)d_in[8];
  const float* kxmap_b = (const float*)d_in[9];
  const float* vxmap_w = (const float*)d_in[10];
  const float* vxmap_b = (const float*)d_in[11];
  const float* qxfeat_w = (const float*)d_in[12];
  const float* qxfeat_b = (const float*)d_in[13];
  const float* kxfeat_w = (const float*)d_in[14];
  const float* kxfeat_b = (const float*)d_in[15];
  const float* proj_w  = (const float*)d_in[16];
  const float* proj_b  = (const float*)d_in[17];
  const float* cout_w  = (const float*)d_in[18];
  const float* cout_b  = (const float*)d_in[19];

  uint8_t* ws = (uint8_t*)d_ws;
  size_t off = 0;
  auto alloc = [&](size_t bytes) -> void* {
    void* p = ws + off;
    off += (bytes + 255) & ~(size_t)255;
    return p;
  };
  float* zp       = (float*)alloc(4096);
  bf16* cmap_wT   = (bf16*)alloc((size_t)2304 * 256 * 2);
  bf16* cout_wT   = (bf16*)alloc((size_t)2304 * 256 * 2);
  bf16* cfeat_wT  = (bf16*)alloc((size_t)288 * 256 * 2);
  bf16* lin_qkv_wT= (bf16*)alloc((size_t)768 * 256 * 2);
  bf16* lin_f_wT  = (bf16*)alloc((size_t)512 * 256 * 2);
  bf16* proj_wT   = (bf16*)alloc((size_t)256 * 256 * 2);
  float* bias_qkv = (float*)alloc(768 * 4);
  float* bias_f   = (float*)alloc(512 * 4);
  bf16* xm_nhwc   = (bf16*)alloc((size_t)Ttok * 256 * 2);
  bf16* xf_nhwc   = (bf16*)alloc((size_t)Ttok * 32 * 2);
  bf16* xc        = (bf16*)alloc((size_t)Ttok * 256 * 2);
  bf16* fc        = (bf16*)alloc((size_t)Ttok * 256 * 2);
  bf16* qkv       = (bf16*)alloc((size_t)Ttok * 768 * 2);
  bf16* attn_out  = xm_nhwc;          // reuse (dead after cmap conv)
  bf16* proj_out  = fc;               // reuse (dead after qkv GEMMs)
  float* convout  = (float*)qkv;      // reuse (dead after attention)
  bf16* zpb = (bf16*)zp;

  k_zero4k<<<4, 256, 0, stream>>>(zp);
  k_permconv<<<(256 * 9 * 256 + 255) / 256, 256, 0, stream>>>(cmap_w, cmap_wT, 256);
  k_permconv<<<(256 * 9 * 256 + 255) / 256, 256, 0, stream>>>(cout_w, cout_wT, 256);
  k_permconv<<<(256 * 9 * 32 + 255) / 256, 256, 0, stream>>>(cfeat_w, cfeat_wT, 32);
  k_castf2b<<<256, 256, 0, stream>>>(qxmap_w, lin_qkv_wT, 65536);
  k_castf2b<<<256, 256, 0, stream>>>(kxmap_w, lin_qkv_wT + 65536, 65536);
  k_castf2b<<<256, 256, 0, stream>>>(vxmap_w, lin_qkv_wT + 131072, 65536);
  k_castf2b<<<256, 256, 0, stream>>>(qxfeat_w, lin_f_wT, 65536);
  k_castf2b<<<256, 256, 0, stream>>>(kxfeat_w, lin_f_wT + 65536, 65536);
  k_castf2b<<<256, 256, 0, stream>>>(proj_w, proj_wT, 65536);
  k_copyf<<<1, 256, 0, stream>>>(qxmap_b, bias_qkv, 256);
  k_copyf<<<1, 256, 0, stream>>>(kxmap_b, bias_qkv + 256, 256);
  k_copyf<<<1, 256, 0, stream>>>(vxmap_b, bias_qkv + 512, 256);
  k_copyf<<<1, 256, 0, stream>>>(qxfeat_b, bias_f, 256);
  k_copyf<<<1, 256, 0, stream>>>(kxfeat_b, bias_f + 256, 256);

  k_tohwc<<<dim3(Bimg * Himg, Wimg / 32, 256 / 32), 256, 0, stream>>>(xmap, xm_nhwc, 256);
  k_tohwc<<<dim3(Bimg * Himg, Wimg / 32, 1), 256, 0, stream>>>(xfeat, xf_nhwc, 32);

  dim3 blk(256);
  const int NT = Ttok / 128;   // 2048 row tiles
  // conv cmap -> xc
  k_gemm<256, 9, 0><<<dim3(NT * 2), blk, 0, stream>>>(
      xm_nhwc, cmap_wT, cmap_b, xc, 256, nullptr, nullptr, zpb, 2);
  // conv cfeat -> fc
  k_gemm<32, 9, 0><<<dim3(NT * 2), blk, 0, stream>>>(
      xf_nhwc, cfeat_wT, cfeat_b, fc, 256, nullptr, nullptr, zpb, 2);
  // v-linear -> qkv[:,512:768]  (plain GEMM, higher occupancy)
  k_gemm<256, 1, 0><<<dim3(NT * 2), blk, 0, stream>>>(
      xc, lin_qkv_wT + 131072, bias_qkv + 512, qkv + 512, 768, nullptr, nullptr, zpb, 2);
  // gated q,k -> qkv[:,0:512]  (dual GEMM, 16-stage pipeline)
  k_gemm_qkv<<<dim3(NT * 4), blk, 0, stream>>>(
      xc, fc, lin_qkv_wT, lin_f_wT, bias_qkv, bias_f, qkv);
  // MFMA window attention
  k_attn_mfma<<<dim3(4096 * 2), blk, 0, stream>>>(qkv, attn_out);
  // proj GEMM
  k_gemm<256, 1, 0><<<dim3(NT * 2), blk, 0, stream>>>(
      attn_out, proj_wT, proj_b, proj_out, 256, nullptr, nullptr, zpb, 2);
  // conv cout + bias + identity -> convout (NHWC fp32)
  k_gemm<256, 9, 2><<<dim3(NT * 2), blk, 0, stream>>>(
      proj_out, cout_wT, cout_b, nullptr, 0, convout, xc, zpb, 2);
  // NHWC -> NCHW final
  k_tochw<<<dim3(Bimg * Himg, Wimg / 32, 256 / 32), 256, 0, stream>>>(convout, (float*)d_out);
}